// Round 11
// baseline (298.779 us; speedup 1.0000x reference)
//
#include <hip/hip_runtime.h>
#include <hip/hip_bf16.h>
#include <math.h>

// SSD post-processing for MI355X.
// (1) softmax->fg scores [B][7][A]; (2) per-(b,c) top-200: sliced-parallel
// histogram (global ghist) + parallel-suffix-scan select + bitonic sort;
// (3) gather+decode; (4) NMS: merge-rank sort -> parallel IoU bitmask ->
// SINGLE-WAVE self-pipelined serial reduce (global_load_lds ring + fine
// s_waitcnt vmcnt(11), no barriers in the loop) -> top-200 output.

#define NCLS 8
#define NFG 7
#define TOPK 200
#define NMSM (NFG * TOPK)   // 1400
#define NCH 22              // ceil(1400/64) 64-wide chunks
#define NPAIRS (NCH * (NCH + 1) / 2)  // 253 upper-triangle chunk pairs
#define BROWS 64
#define BWORDS (BROWS * NCH)          // 1408 u64 per 64-row mask block
#define NRND 11                       // 1 KB global_load_lds rounds per block
#define NBUF 4                        // LDS ring slots (lead=2, reuse dist 4)
#define NSLICE 8
#define LOW_SCORE 0.01f
#define NMS_THR 0.45f
#define BINS 4096
#define CAP 4096

// ---------------- stage 1: softmax + transpose ----------------
__global__ __launch_bounds__(256) void score_kernel(
    const float* __restrict__ logits, float* __restrict__ scores, int A, int total) {
  int i = blockIdx.x * 256 + threadIdx.x;   // i = b*A + a
  if (i >= total) return;
  int b = i / A;
  int a = i - b * A;
  const float* p = logits + (size_t)i * NCLS;
  float x[NCLS];
#pragma unroll
  for (int c = 0; c < NCLS; c++) x[c] = p[c];
  float mx = x[0];
#pragma unroll
  for (int c = 1; c < NCLS; c++) mx = fmaxf(mx, x[c]);
  float e[NCLS];
  float s = 0.0f;
#pragma unroll
  for (int c = 0; c < NCLS; c++) { e[c] = expf(x[c] - mx); s += e[c]; }
  float inv = 1.0f / s;
#pragma unroll
  for (int c = 1; c < NCLS; c++) {
    scores[((size_t)b * NFG + (c - 1)) * A + a] = e[c] * inv;
  }
}

// ---------------- bitonic sort (descending) on shared ulong ----------------
__device__ inline void bitonic_desc(unsigned long long* buf, int P, int tid, int nthr) {
  for (int k = 2; k <= P; k <<= 1) {
    for (int j = k >> 1; j > 0; j >>= 1) {
      __syncthreads();
      for (int i = tid; i < P; i += nthr) {
        int l = i ^ j;
        if (l > i) {
          unsigned long long va = buf[i], vb = buf[l];
          bool descRegion = ((i & k) == 0);
          if (descRegion ? (va < vb) : (va > vb)) { buf[i] = vb; buf[l] = va; }
        }
      }
    }
  }
  __syncthreads();
}

// ---------------- stage 2a: sliced histogram ----------------
__global__ __launch_bounds__(256) void hist_kernel(
    const float* __restrict__ scores, unsigned* __restrict__ ghist, int A) {
  __shared__ unsigned hist[BINS];
  int tid = threadIdx.x;
  int row = blockIdx.x;
  int slice = blockIdx.y;
  int sl = A / NSLICE;                 // 6132, divisible by 4
  for (int i = tid; i < BINS; i += 256) hist[i] = 0;
  __syncthreads();
  const float4* p4 = (const float4*)(scores + (size_t)row * A + (size_t)slice * sl);
  int n4 = sl / 4;
  for (int k = tid; k < n4; k += 256) {
    float4 v = p4[k];
    atomicAdd(&hist[__float_as_uint(v.x) >> 19], 1u);
    atomicAdd(&hist[__float_as_uint(v.y) >> 19], 1u);
    atomicAdd(&hist[__float_as_uint(v.z) >> 19], 1u);
    atomicAdd(&hist[__float_as_uint(v.w) >> 19], 1u);
  }
  __syncthreads();
  unsigned* g = ghist + (size_t)row * BINS;
  for (int i = tid; i < BINS; i += 256) {
    unsigned v = hist[i];
    if (v) atomicAdd(&g[i], v);
  }
}

// ---------------- stage 2b: select threshold + collect + sort ----------------
__global__ __launch_bounds__(256) void select_kernel(
    const float* __restrict__ scores, const unsigned* __restrict__ ghist, int A,
    float* __restrict__ tval, int* __restrict__ tidx) {
  __shared__ unsigned long long buf[CAP];
  __shared__ int sfx[256];
  __shared__ int s_t, s_cnt;
  int tid = threadIdx.x;
  int row = blockIdx.x;  // b*7 + c
  const unsigned* h = ghist + (size_t)row * BINS;
  if (tid == 0) s_cnt = 0;

  // per-thread 16-bin sums, then 8-step suffix scan: sfx[g] = sum bins >= g*16
  int s = 0;
#pragma unroll
  for (int k = 0; k < 16; k++) s += (int)h[tid * 16 + k];
  sfx[tid] = s;
  __syncthreads();
  for (int off = 1; off < 256; off <<= 1) {
    int v = sfx[tid] + ((tid + off < 256) ? sfx[tid + off] : 0);
    __syncthreads();
    sfx[tid] = v;
    __syncthreads();
  }
  // find group g* = max g with sfx[g] >= TOPK, refine within its 16 bins
  if (sfx[0] < TOPK) {
    if (tid == 0) s_t = 0;
  } else {
    bool mine = (sfx[tid] >= TOPK) && (tid == 255 || sfx[tid + 1] < TOPK);
    if (mine) {
      int cum = (tid == 255) ? 0 : sfx[tid + 1];
      int t = tid * 16 + 15;
      for (; t >= tid * 16; t--) { cum += (int)h[t]; if (cum >= TOPK) break; }
      s_t = t;
    }
  }
  __syncthreads();

  // collect candidates (bin >= threshold) with float4 loads
  unsigned tbin = (unsigned)s_t;
  const float4* p4 = (const float4*)(scores + (size_t)row * A);
  int n4 = A / 4;
  for (int k = tid; k < n4; k += 256) {
    float4 v = p4[k];
    float c4[4] = {v.x, v.y, v.z, v.w};
#pragma unroll
    for (int j = 0; j < 4; j++) {
      unsigned key = __float_as_uint(c4[j]);
      if ((key >> 19) >= tbin) {
        int pos = atomicAdd(&s_cnt, 1);
        if (pos < CAP)
          buf[pos] = ((unsigned long long)key << 32) | (unsigned)(~(4 * k + j));
      }
    }
  }
  __syncthreads();
  int cnt = s_cnt; if (cnt > CAP) cnt = CAP;
  int P = 256; while (P < cnt) P <<= 1;
  for (int i = cnt + tid; i < P; i += 256) buf[i] = 0ull;
  __syncthreads();
  bitonic_desc(buf, P, tid, 256);
  if (tid < TOPK) {
    unsigned long long v = buf[tid];
    tval[(size_t)row * TOPK + tid] = __uint_as_float((unsigned)(v >> 32));
    tidx[(size_t)row * TOPK + tid] = (int)(~(unsigned)(v & 0xFFFFFFFFull));
  }
}

// ---------------- stage 3: gather + decode ----------------
__global__ __launch_bounds__(256) void gather_kernel(
    const float* __restrict__ deltas, const float* __restrict__ dbox,
    const float* __restrict__ tval, const int* __restrict__ tidx,
    float* __restrict__ cboxes, float* __restrict__ cscores, int A, int total) {
  int i = blockIdx.x * 256 + threadIdx.x;  // b*NMSM + m
  if (i >= total) return;
  int b = i / NMSM;
  int m = i - b * NMSM;
  int c = m / TOPK;
  int r = m - c * TOPK;
  size_t tk = ((size_t)b * NFG + c) * TOPK + r;
  int a = tidx[tk];
  float v = tval[tk];
  const float* db = dbox + (size_t)a * 4;
  float w = db[2] - db[0];
  float h = db[3] - db[1];
  float cx = db[0] + 0.5f * w;
  float cy = db[1] + 0.5f * h;
  const float* dd = deltas + ((size_t)b * A + a) * 4;
  float pcx = dd[0] / 10.0f * w + cx;
  float pcy = dd[1] / 10.0f * h + cy;
  float pw = expf(dd[2] / 5.0f) * w;
  float ph = expf(dd[3] / 5.0f) * h;
  float x0 = fminf(fmaxf(pcx - 0.5f * pw, 0.0f), 1.0f);
  float y0 = fminf(fmaxf(pcy - 0.5f * ph, 0.0f), 1.0f);
  float x1 = fminf(fmaxf(pcx + 0.5f * pw, 0.0f), 1.0f);
  float y1 = fminf(fmaxf(pcy + 0.5f * ph, 0.0f), 1.0f);
  float* cb = cboxes + (size_t)i * 4;
  cb[0] = x0; cb[1] = y0; cb[2] = x1; cb[3] = y1;
  cscores[i] = v;
}

// ---------------- stage 4a: per-image merge-rank sort ----------------
// The 1400 candidates are 7 per-class lists, each STRICTLY DESCENDING in the
// composite key (score_bits<<32)|~m. Global sorted position = sum over the 7
// lists of count(key > key_e); own list contributes exactly r. 7 independent
// unrolled binary searches per element (ILP hides LDS latency).
__global__ __launch_bounds__(256) void nms_sort_kernel(
    const float* __restrict__ cboxes, const float* __restrict__ cscores,
    float* __restrict__ sx0, float* __restrict__ sy0,
    float* __restrict__ sx1, float* __restrict__ sy1,
    float* __restrict__ sar, int* __restrict__ sord, int* __restrict__ nvalid) {
  __shared__ unsigned long long keys[NMSM];
  __shared__ int s_cnt;
  int tid = threadIdx.x;
  int b = blockIdx.x;
  const float* sc = cscores + (size_t)b * NMSM;
  if (tid == 0) s_cnt = 0;
  __syncthreads();
  int myv = 0;
  for (int m = tid; m < NMSM; m += 256) {
    float s = sc[m];
    unsigned k32 = (s > LOW_SCORE) ? __float_as_uint(s) : 0u;
    if (k32) myv++;
    keys[m] = ((unsigned long long)k32 << 32) | (unsigned)(~m);
  }
  if (myv) atomicAdd(&s_cnt, myv);
  __syncthreads();

  size_t base = (size_t)b * NMSM;
  for (int m = tid; m < NMSM; m += 256) {
    unsigned long long k = keys[m];
    int c = m / TOPK;
    int lo[NFG], hi[NFG];
#pragma unroll
    for (int cc = 0; cc < NFG; cc++) { lo[cc] = 0; hi[cc] = TOPK; }
#pragma unroll
    for (int s8 = 0; s8 < 8; s8++) {
#pragma unroll
      for (int cc = 0; cc < NFG; cc++) {
        if (lo[cc] < hi[cc]) {
          int mid = (lo[cc] + hi[cc]) >> 1;
          if (keys[cc * TOPK + mid] > k) lo[cc] = mid + 1; else hi[cc] = mid;
        }
      }
    }
    int p = 0;
#pragma unroll
    for (int cc = 0; cc < NFG; cc++) p += lo[cc];

    const float* cb = cboxes + (base + m) * 4;
    float off = 4.0f * (float)(c + 1);
    float x0 = cb[0] + off, y0 = cb[1] + off, x1 = cb[2] + off, y1 = cb[3] + off;
    sord[base + p] = m;
    sx0[base + p] = x0; sy0[base + p] = y0;
    sx1[base + p] = x1; sy1[base + p] = y1;
    sar[base + p] = (x1 - x0) * (y1 - y0);
  }
  if (tid == 0) nvalid[b] = s_cnt;
}

// ---------------- stage 4b: suppression bitmask ----------------
// NOTE: only upper-triangle chunk pairs (cj >= ci) are WRITTEN. Words cj < ci
// of a mask row are never initialized (0xAA poison) — consumers MUST NOT
// apply them (wmask in nms_serial_kernel; this broke Round 3).
__global__ __launch_bounds__(64) void nms_mask_kernel(
    const float* __restrict__ sx0, const float* __restrict__ sy0,
    const float* __restrict__ sx1, const float* __restrict__ sy1,
    const float* __restrict__ sar, unsigned long long* __restrict__ mask) {
  int b = blockIdx.y;
  int pair = blockIdx.x;
  int ci = 0, rem = pair;
  while (rem >= NCH - ci) { rem -= NCH - ci; ci++; }
  int cj = ci + rem;   // cj >= ci (upper triangle)
  __shared__ float cx0[64], cy0[64], cx1[64], cy1[64], car[64];
  int t = threadIdx.x;
  size_t base = (size_t)b * NMSM;
  int j = cj * 64 + t;
  if (j < NMSM) {
    cx0[t] = sx0[base + j]; cy0[t] = sy0[base + j];
    cx1[t] = sx1[base + j]; cy1[t] = sy1[base + j];
    car[t] = sar[base + j];
  }
  __syncthreads();
  int i = ci * 64 + t;
  if (i >= NMSM) return;
  float x0 = sx0[base + i], y0 = sy0[base + i];
  float x1 = sx1[base + i], y1 = sy1[base + i], a = sar[base + i];
  unsigned long long bits = 0ull;
#pragma unroll 8
  for (int jj = 0; jj < 64; jj++) {
    int jg = cj * 64 + jj;
    float xl = fmaxf(x0, cx0[jj]);
    float yt = fmaxf(y0, cy0[jj]);
    float xr = fminf(x1, cx1[jj]);
    float yb = fminf(y1, cy1[jj]);
    float inter = fmaxf(xr - xl, 0.0f) * fmaxf(yb - yt, 0.0f);
    float iou = inter / (a + car[jj] - inter);
    if (jg > i && jg < NMSM && iou > NMS_THR) bits |= 1ull << jj;
  }
  mask[(base + i) * NCH + cj] = bits;
}

// ---------------- stage 4c: single-wave pipelined serial reduce ------------
// ONE 64-lane wave per image; no barriers in the loop. Per tick bi:
//   1) issue 11x global_load_lds (1 KB each) for block bi+2 into ring slot
//      (bi+2)%4 (uniform LDS base; HW adds lane*16);
//   2) s_waitcnt vmcnt(11): waits only until block bi+1's 11 loads (issued
//      last tick) retire — the newest 11 stay in flight. Same-wave vmcnt
//      covers our own DMA; no cross-wave visibility needed. This replaces
//      __syncthreads(), whose mandatory vmcnt(0) drain serialized every tick
//      (Rounds 7-10: ~7.5k cyc/tick vs ~2.5k of real work);
//   3) consume block bi from LDS (phases A/B/C as before).
// Last two ticks (nothing to issue) use vmcnt(0) — those loads are 2 ticks
// old, so the drain is free. Slot reuse distance 4 > lead 2.
__global__ __launch_bounds__(64) void nms_serial_kernel(
    const unsigned long long* __restrict__ mask, const int* __restrict__ sord,
    const int* __restrict__ nvalidArr,
    const float* __restrict__ cboxes, const float* __restrict__ cscores,
    float* __restrict__ out, int B) {
  __shared__ __align__(16) unsigned long long rowbuf[NBUF][BWORDS];
  __shared__ unsigned long long skeep[NCH];
  __shared__ int spfx[NCH];
  int b = blockIdx.x;
  int lane = threadIdx.x;
  int nvalid = nvalidArr[b];
  const unsigned long long* M = mask + (size_t)b * NMSM * NCH;

  // alive bit i=1 for sorted positions < nvalid
  unsigned long long remove = 0ull;
  if (lane < NCH) {
    int base = lane * 64;
    if (base + 64 <= nvalid) remove = ~0ull;
    else if (base < nvalid) remove = (~0ull) >> (64 - (nvalid - base));
  }
  bool act = (lane < NCH);
  int li = act ? lane : 0;

  auto stage = [&](int t) {
    const char* srcb = (const char*)(M + (size_t)t * BWORDS) + lane * 16;
    char* dstb = (char*)(rowbuf[t & (NBUF - 1)]);   // WAVE-UNIFORM dst
#pragma unroll
    for (int r = 0; r < NRND; r++) {
      __builtin_amdgcn_global_load_lds(
          (const __attribute__((address_space(1))) void*)(srcb + r * 1024),
          (__attribute__((address_space(3))) void*)(dstb + r * 1024),
          16, 0, 0);
    }
  };

  // prologue: blocks 0 and 1 in flight (22 outstanding)
  stage(0);
  stage(1);

  for (int bi = 0; bi < NCH; bi++) {
    if (bi + 2 < NCH) {
      stage(bi + 2);                                  // newest 11 in flight
      asm volatile("s_waitcnt vmcnt(11)" ::: "memory"); // block bi+1 landed
    } else {
      asm volatile("s_waitcnt vmcnt(0)" ::: "memory");  // tail: drain all
    }
    unsigned long long* rb = rowbuf[bi & (NBUF - 1)];
    // cur = alive word bi, replicated in ALL lanes (VALU chain). Diag words
    // have bits<=d clear, so decided bits are stable.
    unsigned long long cur = __shfl(remove, bi);
    unsigned long long wmask = (act && lane >= bi) ? ~0ull : 0ull;
#pragma unroll 8
    for (int d = 0; d < 64; d++) {
      unsigned long long rowd  = rb[(size_t)d * NCH + li];  // per-lane word
      unsigned long long diagd = rb[(size_t)d * NCH + bi];  // broadcast
      bool kd = (cur >> d) & 1ull;                          // uniform value
      cur    &= ~(kd ? diagd : 0ull);
      remove &= ~(kd ? (rowd & wmask) : 0ull);
    }
    remove = (lane == bi) ? cur : remove;
  }

  if (act) skeep[lane] = remove;
  __syncthreads();   // single wave: trivial; orders LDS for epilogue
  if (lane == 0) {
    int s = 0;
    for (int w = 0; w < NCH; w++) { spfx[w] = s; s += __popcll(skeep[w]); }
  }
  __syncthreads();

  float* ob = out + (size_t)b * TOPK * 4;
  float* os = out + (size_t)B * TOPK * 4 + (size_t)b * TOPK;
  float* ol = out + (size_t)B * TOPK * 5 + (size_t)b * TOPK;
  for (int r = lane; r < TOPK; r += 64) {
    ob[r * 4 + 0] = 0.0f; ob[r * 4 + 1] = 0.0f;
    ob[r * 4 + 2] = 0.0f; ob[r * 4 + 3] = 0.0f;
    os[r] = 0.0f; ol[r] = 0.0f;
  }
  __syncthreads();
  size_t base = (size_t)b * NMSM;
  for (int i = lane; i < NMSM; i += 64) {
    int w = i >> 6;
    unsigned long long kw = skeep[w];
    if ((kw >> (i & 63)) & 1ull) {
      int r = spfx[w] + __popcll(kw & ((1ull << (i & 63)) - 1ull));
      if (r < TOPK) {
        int m = sord[base + i];
        const float* cb = cboxes + (base + m) * 4;
        ob[r * 4 + 0] = cb[0]; ob[r * 4 + 1] = cb[1];
        ob[r * 4 + 2] = cb[2]; ob[r * 4 + 3] = cb[3];
        os[r] = cscores[base + m];
        ol[r] = (float)(m / TOPK + 1);
      }
    }
  }
}

extern "C" void kernel_launch(void* const* d_in, const int* in_sizes, int n_in,
                              void* d_out, int out_size, void* d_ws, size_t ws_size,
                              hipStream_t stream) {
  const float* logits = (const float*)d_in[0];
  const float* deltas = (const float*)d_in[1];
  const float* dbox   = (const float*)d_in[2];
  int A = in_sizes[2] / 4;
  int B = in_sizes[0] / (A * NCLS);
  int NROWS = B * NFG;
  float* out = (float*)d_out;

  // workspace layout
  float* scores_ws = (float*)d_ws;                                  // B*7*A floats
  float* tval = scores_ws + (size_t)B * NFG * A;                    // B*7*200
  int*   tidx = (int*)(tval + (size_t)B * NFG * TOPK);              // B*7*200
  float* cboxes = (float*)(tidx + (size_t)B * NFG * TOPK);          // B*1400*4
  float* cscores = cboxes + (size_t)B * NMSM * 4;                   // B*1400
  unsigned* ghist = (unsigned*)(cscores + (size_t)B * NMSM);        // 224*4096 u32

  // NMS scratch aliased onto the scores buffer (dead after select_kernel):
  //   mask: B*1400*22 u64 = 7.885 MB at offset 0 (last image's last block
  //   stages 8 padded rows = 1.4 KB past its region — inside the 8 MB window)
  //   sorted arrays at +8 MB (2,097,152 floats)
  unsigned long long* mask = (unsigned long long*)scores_ws;
  float* sbase = scores_ws + 2097152;
  size_t n1 = (size_t)B * NMSM;
  float* sx0 = sbase;            float* sy0 = sbase + n1;
  float* sx1 = sbase + 2 * n1;   float* sy1 = sbase + 3 * n1;
  float* sar = sbase + 4 * n1;
  int*   sord = (int*)(sbase + 5 * n1);
  int*   nvalid = (int*)(sbase + 6 * n1);

  hipMemsetAsync(ghist, 0, (size_t)NROWS * BINS * sizeof(unsigned), stream);
  int total = B * A;
  score_kernel<<<(total + 255) / 256, 256, 0, stream>>>(logits, scores_ws, A, total);
  hist_kernel<<<dim3(NROWS, NSLICE), 256, 0, stream>>>(scores_ws, ghist, A);
  select_kernel<<<NROWS, 256, 0, stream>>>(scores_ws, ghist, A, tval, tidx);
  int gtotal = B * NMSM;
  gather_kernel<<<(gtotal + 255) / 256, 256, 0, stream>>>(deltas, dbox, tval, tidx,
                                                          cboxes, cscores, A, gtotal);
  nms_sort_kernel<<<B, 256, 0, stream>>>(cboxes, cscores, sx0, sy0, sx1, sy1, sar,
                                         sord, nvalid);
  nms_mask_kernel<<<dim3(NPAIRS, B), 64, 0, stream>>>(sx0, sy0, sx1, sy1, sar, mask);
  nms_serial_kernel<<<B, 64, 0, stream>>>(mask, sord, nvalid, cboxes, cscores, out, B);
}

// Round 12
// 234.236 us; speedup vs baseline: 1.2755x; 1.2755x over previous
//
#include <hip/hip_runtime.h>
#include <hip/hip_bf16.h>
#include <math.h>

// SSD post-processing for MI355X.
// (1) softmax->fg scores [B][7][A]; (2) per-(b,c) top-200: sliced-parallel
// histogram (global ghist) + parallel-suffix-scan select + bitonic sort;
// (3) gather+decode; (4) NMS: merge-rank sort -> parallel IoU bitmask ->
// single-wave pipelined serial reduce with EARLY EXIT at 200 keeps -> output.

#define NCLS 8
#define NFG 7
#define TOPK 200
#define NMSM (NFG * TOPK)   // 1400
#define NCH 22              // ceil(1400/64) 64-wide chunks
#define NPAIRS (NCH * (NCH + 1) / 2)  // 253 upper-triangle chunk pairs
#define BROWS 64
#define BWORDS (BROWS * NCH)          // 1408 u64 per 64-row mask block
#define NRND 11                       // 1 KB global_load_lds rounds per block
#define NBUF 4                        // LDS ring slots (lead=2, reuse dist 4)
#define NSLICE 8
#define LOW_SCORE 0.01f
#define NMS_THR 0.45f
#define BINS 4096
#define CAP 4096

// ---------------- stage 1: softmax + transpose ----------------
__global__ __launch_bounds__(256) void score_kernel(
    const float* __restrict__ logits, float* __restrict__ scores, int A, int total) {
  int i = blockIdx.x * 256 + threadIdx.x;   // i = b*A + a
  if (i >= total) return;
  int b = i / A;
  int a = i - b * A;
  const float* p = logits + (size_t)i * NCLS;
  float x[NCLS];
#pragma unroll
  for (int c = 0; c < NCLS; c++) x[c] = p[c];
  float mx = x[0];
#pragma unroll
  for (int c = 1; c < NCLS; c++) mx = fmaxf(mx, x[c]);
  float e[NCLS];
  float s = 0.0f;
#pragma unroll
  for (int c = 0; c < NCLS; c++) { e[c] = expf(x[c] - mx); s += e[c]; }
  float inv = 1.0f / s;
#pragma unroll
  for (int c = 1; c < NCLS; c++) {
    scores[((size_t)b * NFG + (c - 1)) * A + a] = e[c] * inv;
  }
}

// ---------------- bitonic sort (descending) on shared ulong ----------------
__device__ inline void bitonic_desc(unsigned long long* buf, int P, int tid, int nthr) {
  for (int k = 2; k <= P; k <<= 1) {
    for (int j = k >> 1; j > 0; j >>= 1) {
      __syncthreads();
      for (int i = tid; i < P; i += nthr) {
        int l = i ^ j;
        if (l > i) {
          unsigned long long va = buf[i], vb = buf[l];
          bool descRegion = ((i & k) == 0);
          if (descRegion ? (va < vb) : (va > vb)) { buf[i] = vb; buf[l] = va; }
        }
      }
    }
  }
  __syncthreads();
}

// ---------------- stage 2a: sliced histogram ----------------
__global__ __launch_bounds__(256) void hist_kernel(
    const float* __restrict__ scores, unsigned* __restrict__ ghist, int A) {
  __shared__ unsigned hist[BINS];
  int tid = threadIdx.x;
  int row = blockIdx.x;
  int slice = blockIdx.y;
  int sl = A / NSLICE;                 // 6132, divisible by 4
  for (int i = tid; i < BINS; i += 256) hist[i] = 0;
  __syncthreads();
  const float4* p4 = (const float4*)(scores + (size_t)row * A + (size_t)slice * sl);
  int n4 = sl / 4;
  for (int k = tid; k < n4; k += 256) {
    float4 v = p4[k];
    atomicAdd(&hist[__float_as_uint(v.x) >> 19], 1u);
    atomicAdd(&hist[__float_as_uint(v.y) >> 19], 1u);
    atomicAdd(&hist[__float_as_uint(v.z) >> 19], 1u);
    atomicAdd(&hist[__float_as_uint(v.w) >> 19], 1u);
  }
  __syncthreads();
  unsigned* g = ghist + (size_t)row * BINS;
  for (int i = tid; i < BINS; i += 256) {
    unsigned v = hist[i];
    if (v) atomicAdd(&g[i], v);
  }
}

// ---------------- stage 2b: select threshold + collect + sort ----------------
__global__ __launch_bounds__(256) void select_kernel(
    const float* __restrict__ scores, const unsigned* __restrict__ ghist, int A,
    float* __restrict__ tval, int* __restrict__ tidx) {
  __shared__ unsigned long long buf[CAP];
  __shared__ int sfx[256];
  __shared__ int s_t, s_cnt;
  int tid = threadIdx.x;
  int row = blockIdx.x;  // b*7 + c
  const unsigned* h = ghist + (size_t)row * BINS;
  if (tid == 0) s_cnt = 0;

  // per-thread 16-bin sums, then 8-step suffix scan: sfx[g] = sum bins >= g*16
  int s = 0;
#pragma unroll
  for (int k = 0; k < 16; k++) s += (int)h[tid * 16 + k];
  sfx[tid] = s;
  __syncthreads();
  for (int off = 1; off < 256; off <<= 1) {
    int v = sfx[tid] + ((tid + off < 256) ? sfx[tid + off] : 0);
    __syncthreads();
    sfx[tid] = v;
    __syncthreads();
  }
  // find group g* = max g with sfx[g] >= TOPK, refine within its 16 bins
  if (sfx[0] < TOPK) {
    if (tid == 0) s_t = 0;
  } else {
    bool mine = (sfx[tid] >= TOPK) && (tid == 255 || sfx[tid + 1] < TOPK);
    if (mine) {
      int cum = (tid == 255) ? 0 : sfx[tid + 1];
      int t = tid * 16 + 15;
      for (; t >= tid * 16; t--) { cum += (int)h[t]; if (cum >= TOPK) break; }
      s_t = t;
    }
  }
  __syncthreads();

  // collect candidates (bin >= threshold) with float4 loads
  unsigned tbin = (unsigned)s_t;
  const float4* p4 = (const float4*)(scores + (size_t)row * A);
  int n4 = A / 4;
  for (int k = tid; k < n4; k += 256) {
    float4 v = p4[k];
    float c4[4] = {v.x, v.y, v.z, v.w};
#pragma unroll
    for (int j = 0; j < 4; j++) {
      unsigned key = __float_as_uint(c4[j]);
      if ((key >> 19) >= tbin) {
        int pos = atomicAdd(&s_cnt, 1);
        if (pos < CAP)
          buf[pos] = ((unsigned long long)key << 32) | (unsigned)(~(4 * k + j));
      }
    }
  }
  __syncthreads();
  int cnt = s_cnt; if (cnt > CAP) cnt = CAP;
  int P = 256; while (P < cnt) P <<= 1;
  for (int i = cnt + tid; i < P; i += 256) buf[i] = 0ull;
  __syncthreads();
  bitonic_desc(buf, P, tid, 256);
  if (tid < TOPK) {
    unsigned long long v = buf[tid];
    tval[(size_t)row * TOPK + tid] = __uint_as_float((unsigned)(v >> 32));
    tidx[(size_t)row * TOPK + tid] = (int)(~(unsigned)(v & 0xFFFFFFFFull));
  }
}

// ---------------- stage 3: gather + decode ----------------
__global__ __launch_bounds__(256) void gather_kernel(
    const float* __restrict__ deltas, const float* __restrict__ dbox,
    const float* __restrict__ tval, const int* __restrict__ tidx,
    float* __restrict__ cboxes, float* __restrict__ cscores, int A, int total) {
  int i = blockIdx.x * 256 + threadIdx.x;  // b*NMSM + m
  if (i >= total) return;
  int b = i / NMSM;
  int m = i - b * NMSM;
  int c = m / TOPK;
  int r = m - c * TOPK;
  size_t tk = ((size_t)b * NFG + c) * TOPK + r;
  int a = tidx[tk];
  float v = tval[tk];
  const float* db = dbox + (size_t)a * 4;
  float w = db[2] - db[0];
  float h = db[3] - db[1];
  float cx = db[0] + 0.5f * w;
  float cy = db[1] + 0.5f * h;
  const float* dd = deltas + ((size_t)b * A + a) * 4;
  float pcx = dd[0] / 10.0f * w + cx;
  float pcy = dd[1] / 10.0f * h + cy;
  float pw = expf(dd[2] / 5.0f) * w;
  float ph = expf(dd[3] / 5.0f) * h;
  float x0 = fminf(fmaxf(pcx - 0.5f * pw, 0.0f), 1.0f);
  float y0 = fminf(fmaxf(pcy - 0.5f * ph, 0.0f), 1.0f);
  float x1 = fminf(fmaxf(pcx + 0.5f * pw, 0.0f), 1.0f);
  float y1 = fminf(fmaxf(pcy + 0.5f * ph, 0.0f), 1.0f);
  float* cb = cboxes + (size_t)i * 4;
  cb[0] = x0; cb[1] = y0; cb[2] = x1; cb[3] = y1;
  cscores[i] = v;
}

// ---------------- stage 4a: per-image merge-rank sort ----------------
// The 1400 candidates are 7 per-class lists, each STRICTLY DESCENDING in the
// composite key (score_bits<<32)|~m. Global sorted position = sum over the 7
// lists of count(key > key_e); own list contributes exactly r. 7 independent
// unrolled binary searches per element (ILP hides LDS latency).
__global__ __launch_bounds__(256) void nms_sort_kernel(
    const float* __restrict__ cboxes, const float* __restrict__ cscores,
    float* __restrict__ sx0, float* __restrict__ sy0,
    float* __restrict__ sx1, float* __restrict__ sy1,
    float* __restrict__ sar, int* __restrict__ sord, int* __restrict__ nvalid) {
  __shared__ unsigned long long keys[NMSM];
  __shared__ int s_cnt;
  int tid = threadIdx.x;
  int b = blockIdx.x;
  const float* sc = cscores + (size_t)b * NMSM;
  if (tid == 0) s_cnt = 0;
  __syncthreads();
  int myv = 0;
  for (int m = tid; m < NMSM; m += 256) {
    float s = sc[m];
    unsigned k32 = (s > LOW_SCORE) ? __float_as_uint(s) : 0u;
    if (k32) myv++;
    keys[m] = ((unsigned long long)k32 << 32) | (unsigned)(~m);
  }
  if (myv) atomicAdd(&s_cnt, myv);
  __syncthreads();

  size_t base = (size_t)b * NMSM;
  for (int m = tid; m < NMSM; m += 256) {
    unsigned long long k = keys[m];
    int c = m / TOPK;
    int lo[NFG], hi[NFG];
#pragma unroll
    for (int cc = 0; cc < NFG; cc++) { lo[cc] = 0; hi[cc] = TOPK; }
#pragma unroll
    for (int s8 = 0; s8 < 8; s8++) {
#pragma unroll
      for (int cc = 0; cc < NFG; cc++) {
        if (lo[cc] < hi[cc]) {
          int mid = (lo[cc] + hi[cc]) >> 1;
          if (keys[cc * TOPK + mid] > k) lo[cc] = mid + 1; else hi[cc] = mid;
        }
      }
    }
    int p = 0;
#pragma unroll
    for (int cc = 0; cc < NFG; cc++) p += lo[cc];

    const float* cb = cboxes + (base + m) * 4;
    float off = 4.0f * (float)(c + 1);
    float x0 = cb[0] + off, y0 = cb[1] + off, x1 = cb[2] + off, y1 = cb[3] + off;
    sord[base + p] = m;
    sx0[base + p] = x0; sy0[base + p] = y0;
    sx1[base + p] = x1; sy1[base + p] = y1;
    sar[base + p] = (x1 - x0) * (y1 - y0);
  }
  if (tid == 0) nvalid[b] = s_cnt;
}

// ---------------- stage 4b: suppression bitmask ----------------
// NOTE: only upper-triangle chunk pairs (cj >= ci) are WRITTEN. Words cj < ci
// of a mask row are never initialized (0xAA poison) — consumers MUST NOT
// apply them (wmask in nms_serial_kernel; this broke Round 3).
__global__ __launch_bounds__(64) void nms_mask_kernel(
    const float* __restrict__ sx0, const float* __restrict__ sy0,
    const float* __restrict__ sx1, const float* __restrict__ sy1,
    const float* __restrict__ sar, unsigned long long* __restrict__ mask) {
  int b = blockIdx.y;
  int pair = blockIdx.x;
  int ci = 0, rem = pair;
  while (rem >= NCH - ci) { rem -= NCH - ci; ci++; }
  int cj = ci + rem;   // cj >= ci (upper triangle)
  __shared__ float cx0[64], cy0[64], cx1[64], cy1[64], car[64];
  int t = threadIdx.x;
  size_t base = (size_t)b * NMSM;
  int j = cj * 64 + t;
  if (j < NMSM) {
    cx0[t] = sx0[base + j]; cy0[t] = sy0[base + j];
    cx1[t] = sx1[base + j]; cy1[t] = sy1[base + j];
    car[t] = sar[base + j];
  }
  __syncthreads();
  int i = ci * 64 + t;
  if (i >= NMSM) return;
  float x0 = sx0[base + i], y0 = sy0[base + i];
  float x1 = sx1[base + i], y1 = sy1[base + i], a = sar[base + i];
  unsigned long long bits = 0ull;
#pragma unroll 8
  for (int jj = 0; jj < 64; jj++) {
    int jg = cj * 64 + jj;
    float xl = fmaxf(x0, cx0[jj]);
    float yt = fmaxf(y0, cy0[jj]);
    float xr = fminf(x1, cx1[jj]);
    float yb = fminf(y1, cy1[jj]);
    float inter = fmaxf(xr - xl, 0.0f) * fmaxf(yb - yt, 0.0f);
    float iou = inter / (a + car[jj] - inter);
    if (jg > i && jg < NMSM && iou > NMS_THR) bits |= 1ull << jj;
  }
  mask[(base + i) * NCH + cj] = bits;
}

// ---------------- stage 4c: pipelined serial reduce + EARLY EXIT -----------
// ONE 64-lane wave per image. Per tick bi: issue DMA for block bi+2 (uniform
// LDS base), vmcnt(11) for block bi+1, consume block bi. EARLY EXIT: output
// needs only the FIRST 200 kept candidates; after committing block bi, if
// cumulative keeps >= 200, every later element's rank is >= 200 (prefix sums
// already >= 200) so their skeep words can be zeroed — break out. Typical
// data keeps most candidates -> exit after ~4 of 22 blocks. Worst case
// degenerates to the full 22 (no slower than Round 11).
__global__ __launch_bounds__(64) void nms_serial_kernel(
    const unsigned long long* __restrict__ mask, const int* __restrict__ sord,
    const int* __restrict__ nvalidArr,
    const float* __restrict__ cboxes, const float* __restrict__ cscores,
    float* __restrict__ out, int B) {
  __shared__ __align__(16) unsigned long long rowbuf[NBUF][BWORDS];
  __shared__ unsigned long long skeep[NCH];
  __shared__ int spfx[NCH];
  int b = blockIdx.x;
  int lane = threadIdx.x;
  int nvalid = nvalidArr[b];
  const unsigned long long* M = mask + (size_t)b * NMSM * NCH;

  // alive bit i=1 for sorted positions < nvalid
  unsigned long long remove = 0ull;
  if (lane < NCH) {
    int base = lane * 64;
    if (base + 64 <= nvalid) remove = ~0ull;
    else if (base < nvalid) remove = (~0ull) >> (64 - (nvalid - base));
  }
  bool act = (lane < NCH);
  int li = act ? lane : 0;

  auto stage = [&](int t) {
    const char* srcb = (const char*)(M + (size_t)t * BWORDS) + lane * 16;
    char* dstb = (char*)(rowbuf[t & (NBUF - 1)]);   // WAVE-UNIFORM dst
#pragma unroll
    for (int r = 0; r < NRND; r++) {
      __builtin_amdgcn_global_load_lds(
          (const __attribute__((address_space(1))) void*)(srcb + r * 1024),
          (__attribute__((address_space(3))) void*)(dstb + r * 1024),
          16, 0, 0);
    }
  };

  // prologue: blocks 0 and 1 in flight (22 outstanding)
  stage(0);
  stage(1);

  int kept = 0;
  int processed = 0;
  for (int bi = 0; bi < NCH; bi++) {
    if (bi + 2 < NCH) {
      stage(bi + 2);                                  // newest 11 in flight
      asm volatile("s_waitcnt vmcnt(11)" ::: "memory"); // block bi+1 landed
    } else {
      asm volatile("s_waitcnt vmcnt(0)" ::: "memory");  // tail: drain all
    }
    unsigned long long* rb = rowbuf[bi & (NBUF - 1)];
    // cur = alive word bi, replicated in ALL lanes (VALU chain). Diag words
    // have bits<=d clear, so decided bits are stable.
    unsigned long long cur = __shfl(remove, bi);
    unsigned long long wmask = (act && lane >= bi) ? ~0ull : 0ull;
#pragma unroll 8
    for (int d = 0; d < 64; d++) {
      unsigned long long rowd  = rb[(size_t)d * NCH + li];  // per-lane word
      unsigned long long diagd = rb[(size_t)d * NCH + bi];  // broadcast
      bool kd = (cur >> d) & 1ull;                          // uniform value
      cur    &= ~(kd ? diagd : 0ull);
      remove &= ~(kd ? (rowd & wmask) : 0ull);
    }
    remove = (lane == bi) ? cur : remove;
    kept += (int)__popcll(cur);       // cur uniform across lanes
    processed = bi + 1;
    if (kept >= TOPK) break;          // later ranks provably >= 200
  }

  // unprocessed blocks: rank >= kept >= 200 -> zero their keep words
  if (act) skeep[lane] = (lane < processed) ? remove : 0ull;
  __syncthreads();   // also drains abandoned in-flight DMA (vmcnt(0))
  if (lane == 0) {
    int s = 0;
    for (int w = 0; w < NCH; w++) { spfx[w] = s; s += __popcll(skeep[w]); }
  }
  __syncthreads();

  float* ob = out + (size_t)b * TOPK * 4;
  float* os = out + (size_t)B * TOPK * 4 + (size_t)b * TOPK;
  float* ol = out + (size_t)B * TOPK * 5 + (size_t)b * TOPK;
  for (int r = lane; r < TOPK; r += 64) {
    ob[r * 4 + 0] = 0.0f; ob[r * 4 + 1] = 0.0f;
    ob[r * 4 + 2] = 0.0f; ob[r * 4 + 3] = 0.0f;
    os[r] = 0.0f; ol[r] = 0.0f;
  }
  __syncthreads();
  size_t base = (size_t)b * NMSM;
  for (int i = lane; i < NMSM; i += 64) {
    int w = i >> 6;
    unsigned long long kw = skeep[w];
    if ((kw >> (i & 63)) & 1ull) {
      int r = spfx[w] + __popcll(kw & ((1ull << (i & 63)) - 1ull));
      if (r < TOPK) {
        int m = sord[base + i];
        const float* cb = cboxes + (base + m) * 4;
        ob[r * 4 + 0] = cb[0]; ob[r * 4 + 1] = cb[1];
        ob[r * 4 + 2] = cb[2]; ob[r * 4 + 3] = cb[3];
        os[r] = cscores[base + m];
        ol[r] = (float)(m / TOPK + 1);
      }
    }
  }
}

extern "C" void kernel_launch(void* const* d_in, const int* in_sizes, int n_in,
                              void* d_out, int out_size, void* d_ws, size_t ws_size,
                              hipStream_t stream) {
  const float* logits = (const float*)d_in[0];
  const float* deltas = (const float*)d_in[1];
  const float* dbox   = (const float*)d_in[2];
  int A = in_sizes[2] / 4;
  int B = in_sizes[0] / (A * NCLS);
  int NROWS = B * NFG;
  float* out = (float*)d_out;

  // workspace layout
  float* scores_ws = (float*)d_ws;                                  // B*7*A floats
  float* tval = scores_ws + (size_t)B * NFG * A;                    // B*7*200
  int*   tidx = (int*)(tval + (size_t)B * NFG * TOPK);              // B*7*200
  float* cboxes = (float*)(tidx + (size_t)B * NFG * TOPK);          // B*1400*4
  float* cscores = cboxes + (size_t)B * NMSM * 4;                   // B*1400
  unsigned* ghist = (unsigned*)(cscores + (size_t)B * NMSM);        // 224*4096 u32

  // NMS scratch aliased onto the scores buffer (dead after select_kernel):
  //   mask: B*1400*22 u64 = 7.885 MB at offset 0 (last image's last block
  //   stages 8 padded rows = 1.4 KB past its region — inside the 8 MB window)
  //   sorted arrays at +8 MB (2,097,152 floats)
  unsigned long long* mask = (unsigned long long*)scores_ws;
  float* sbase = scores_ws + 2097152;
  size_t n1 = (size_t)B * NMSM;
  float* sx0 = sbase;            float* sy0 = sbase + n1;
  float* sx1 = sbase + 2 * n1;   float* sy1 = sbase + 3 * n1;
  float* sar = sbase + 4 * n1;
  int*   sord = (int*)(sbase + 5 * n1);
  int*   nvalid = (int*)(sbase + 6 * n1);

  hipMemsetAsync(ghist, 0, (size_t)NROWS * BINS * sizeof(unsigned), stream);
  int total = B * A;
  score_kernel<<<(total + 255) / 256, 256, 0, stream>>>(logits, scores_ws, A, total);
  hist_kernel<<<dim3(NROWS, NSLICE), 256, 0, stream>>>(scores_ws, ghist, A);
  select_kernel<<<NROWS, 256, 0, stream>>>(scores_ws, ghist, A, tval, tidx);
  int gtotal = B * NMSM;
  gather_kernel<<<(gtotal + 255) / 256, 256, 0, stream>>>(deltas, dbox, tval, tidx,
                                                          cboxes, cscores, A, gtotal);
  nms_sort_kernel<<<B, 256, 0, stream>>>(cboxes, cscores, sx0, sy0, sx1, sy1, sar,
                                         sord, nvalid);
  nms_mask_kernel<<<dim3(NPAIRS, B), 64, 0, stream>>>(sx0, sy0, sx1, sy1, sar, mask);
  nms_serial_kernel<<<B, 64, 0, stream>>>(mask, sord, nvalid, cboxes, cscores, out, B);
}